// Round 11
// baseline (1721.081 us; speedup 1.0000x reference)
//
#include <hip/hip_runtime.h>
#include <stdint.h>

#define Hh   51
#define Bsz  1024
#define Tin  512
#define Ttot 576      // Tin + future(64)
#define NBB  16       // batches per block (MFMA N)
#define NW   4        // waves per block, 1 per SIMD
#define BLK  (NW*64)  // 256
#define BST  136      // per-batch k-stride (uint16) = 68 dwords (no 4-way alias)
#define NTL  4        // max M-tiles per wave (wave0: 4, others: 3; 13 total)

typedef __attribute__((ext_vector_type(8))) short short8;   // 8 x bf16 frag
typedef __attribute__((ext_vector_type(4))) float f32x4;    // C/D frag

__device__ __forceinline__ float fsig(float x){ return 1.f/(1.f+__expf(-x)); }
__device__ __forceinline__ float ftanh(float x){ return 2.f*fsig(2.f*x)-1.f; }
__device__ __forceinline__ uint16_t f2bf(float f){
    union{float f;uint32_t u;} v; v.f=f;
    return (uint16_t)((v.u + 0x7fffu + ((v.u>>16)&1u)) >> 16);   // RNE
}
__device__ __forceinline__ float bf2f(uint16_t h){
    union{uint32_t u;float f;} v; v.u=(uint32_t)h<<16; return v.f;
}
#define MFMA __builtin_amdgcn_mfma_f32_16x16x32_bf16

// 4 waves x (3..4) M-tiles; logical gate-row m = 4*unit+gate so each lane's 4
// C-regs are the 4 gates of one unit (in-register cell). NO global memory ops
// inside the step loop: outputs buffered in LDS (obuf) and dumped at the end,
// so the compiler's vmcnt(0) drain before each s_barrier is free (R8-R10 paid
// global store/ack latency at every barrier, ~invariant 1.25 ms floor).
__global__ __launch_bounds__(BLK, 1)
void lstm_mfma4(const float* __restrict__ inp,    // [B, Tin]
                const float* __restrict__ Wih1,   // [204, 1]
                const float* __restrict__ Whh1,   // [204, 51]
                const float* __restrict__ bih1,   // [204]
                const float* __restrict__ bhh1,   // [204]
                const float* __restrict__ Wih2,   // [204, 51]
                const float* __restrict__ Whh2,   // [204, 51]
                const float* __restrict__ bih2,   // [204]
                const float* __restrict__ bhh2,   // [204]
                const float* __restrict__ Wl,     // [1, 51]
                const float* __restrict__ blp,    // [1]
                float* __restrict__ outp)         // [B, Ttot]
{
    const int tid = threadIdx.x;
    const int wv  = tid >> 6, ln = tid & 63;
    const int quad = ln >> 4, nn = ln & 15;
    const int b0  = blockIdx.x * NBB;

    __shared__ __align__(16) uint16_t Bhi[2][NBB*BST];   // 8704 B
    __shared__ __align__(16) uint16_t Blo[2][NBB*BST];   // 8704 B
    __shared__ float obuf[Ttot*NBB];                     // 36864 B
    __shared__ float wsum[NW*NBB];                       // 256 B

    for (int k = tid; k < NBB*BST; k += BLK) {
        Bhi[0][k] = 0; Bhi[1][k] = 0; Blo[0][k] = 0; Blo[1][k] = 0;
    }
    if (tid < NW*NBB) wsum[tid] = 0.f;

    // ---- A fragments for up to 4 tiles (tile id = wv + 4*tl) ----
    short8 a1hi[NTL][2], a1lo[NTL][2], a2hi[NTL][4], a2lo[NTL][4];
    f32x4 bias1[NTL], bias2[NTL], wih1v[NTL];
    float wlu[NTL]; int ut[NTL]; bool tv[NTL], uvt[NTL];
#pragma unroll
    for (int tl = 0; tl < NTL; ++tl) {
        const int tile = wv + 4*tl;
        tv[tl] = (tile < 13);
        const int lr = 16*tile + nn;              // this lane's logical A row
        const int ua = lr >> 2, ga = lr & 3;
        const bool av = tv[tl] && (ua < Hh);
        const int pr = av ? (ga*Hh + ua) : 0;     // physical PyTorch row
#pragma unroll
        for (int s = 0; s < 2; ++s)
#pragma unroll
            for (int j = 0; j < 8; ++j) {
                int k = 32*s + quad*8 + j;
                float w = (av && k < Hh) ? Whh1[pr*Hh + k] : 0.f;
                uint16_t hh = f2bf(w);
                a1hi[tl][s][j] = (short)hh;
                a1lo[tl][s][j] = (short)f2bf(w - bf2f(hh));
            }
#pragma unroll
        for (int s = 0; s < 4; ++s)
#pragma unroll
            for (int j = 0; j < 8; ++j) {
                int k = 32*s + quad*8 + j;
                float w = 0.f;
                if (av) {
                    if (k < Hh)                    w = Wih2[pr*Hh + k];
                    else if (k >= 64 && k < 64+Hh) w = Whh2[pr*Hh + (k-64)];
                }
                uint16_t hh = f2bf(w);
                a2hi[tl][s][j] = (short)hh;
                a2lo[tl][s][j] = (short)f2bf(w - bf2f(hh));
            }
        const int u = 4*tile + quad;              // unit this lane's cell owns
        ut[tl] = u; uvt[tl] = tv[tl] && (u < Hh);
#pragma unroll
        for (int i = 0; i < 4; ++i) {
            int pri = uvt[tl] ? (i*Hh + u) : 0;
            bias1[tl][i] = uvt[tl] ? (bih1[pri] + bhh1[pri]) : 0.f;
            bias2[tl][i] = uvt[tl] ? (bih2[pri] + bhh2[pri]) : 0.f;
            wih1v[tl][i] = uvt[tl] ? Wih1[pri] : 0.f;
        }
        wlu[tl] = uvt[tl] ? Wl[ut[tl]] : 0.f;
    }
    const float blv = blp[0];
    float c1[NTL] = {0.f,0.f,0.f,0.f}, c2[NTL] = {0.f,0.f,0.f,0.f};
    float xreg = inp[(size_t)(b0 + nn)*Tin];      // x for t=0

    __syncthreads();

    for (int t = 0; t < Ttot; ++t) {
        const int p0 = t & 1, p1 = p0 ^ 1;

        // ---- front: previous step's output -> obuf (wave NW-1) and x (future)
        float x = xreg;
        if (t > 0 && (t >= Tin || wv == NW-1)) {
            float osum = blv;
#pragma unroll
            for (int w = 0; w < NW; ++w) osum += wsum[w*NBB + nn];
            if (wv == NW-1 && ln < NBB) obuf[(t-1)*NBB + ln] = osum;
            if (t >= Tin) x = osum;
        }
        // x prefetch for t+1: issued here, consumed at loop end (covered by phase work)
        float xnext = 0.f;
        if (t + 1 < Tin) xnext = inp[(size_t)(b0 + nn)*Tin + t + 1];

        // ================= L1: GEMM + in-register cells =================
        {
            const uint16_t* rb = &Bhi[p1][nn*BST + quad*8];
            const uint16_t* rl = &Blo[p1][nn*BST + quad*8];
            short8 h0 = *(const short8*)(rb),  h1f = *(const short8*)(rb + 32);
            short8 l0 = *(const short8*)(rl),  l1f = *(const short8*)(rl + 32);
#pragma unroll
            for (int tl = 0; tl < NTL; ++tl) {
                if (!tv[tl]) continue;                     // wave-uniform skip
                f32x4 aA, aB = {0.f,0.f,0.f,0.f};
#pragma unroll
                for (int i = 0; i < 4; ++i)
                    aA[i] = __builtin_fmaf(wih1v[tl][i], x, bias1[tl][i]);
                aA = MFMA(a1hi[tl][0], h0,  aA, 0,0,0);
                aB = MFMA(a1hi[tl][1], h1f, aB, 0,0,0);
                aA = MFMA(a1lo[tl][0], h0,  aA, 0,0,0);
                aB = MFMA(a1lo[tl][1], h1f, aB, 0,0,0);
                aA = MFMA(a1hi[tl][0], l0,  aA, 0,0,0);
                aB = MFMA(a1hi[tl][1], l1f, aB, 0,0,0);
                float vi = aA[0]+aB[0], vf = aA[1]+aB[1];
                float vg = aA[2]+aB[2], vo = aA[3]+aB[3];
                c1[tl] = __builtin_fmaf(fsig(vf), c1[tl], fsig(vi)*ftanh(vg));
                float h1n = fsig(vo) * ftanh(c1[tl]);
                if (uvt[tl]) {
                    uint16_t hh = f2bf(h1n);
                    int ad = nn*BST + ut[tl];
                    Bhi[p0][ad] = hh; Blo[p0][ad] = f2bf(h1n - bf2f(hh));
                }
            }
        }
        __syncthreads();                                   // bar 1

        // ============ L2: GEMM over [h1_t | 0 | h2_{t-1}] + cells ============
        {
            const uint16_t* rb0 = &Bhi[p0][nn*BST + quad*8];   // h1_t
            const uint16_t* rl0 = &Blo[p0][nn*BST + quad*8];
            const uint16_t* rb1 = &Bhi[p1][nn*BST + quad*8];   // h2_{t-1}
            const uint16_t* rl1 = &Blo[p1][nn*BST + quad*8];
            short8 s0h = *(const short8*)(rb0),      s1h = *(const short8*)(rb0 + 32);
            short8 s0l = *(const short8*)(rl0),      s1l = *(const short8*)(rl0 + 32);
            short8 s2h = *(const short8*)(rb1 + 64), s3h = *(const short8*)(rb1 + 96);
            short8 s2l = *(const short8*)(rl1 + 64), s3l = *(const short8*)(rl1 + 96);
            float part = 0.f;
#pragma unroll
            for (int tl = 0; tl < NTL; ++tl) {
                if (!tv[tl]) continue;
                f32x4 aA = bias2[tl], aB = {0.f,0.f,0.f,0.f};
                aA = MFMA(a2hi[tl][0], s0h, aA, 0,0,0);
                aB = MFMA(a2hi[tl][1], s1h, aB, 0,0,0);
                aA = MFMA(a2lo[tl][0], s0h, aA, 0,0,0);
                aB = MFMA(a2lo[tl][1], s1h, aB, 0,0,0);
                aA = MFMA(a2hi[tl][0], s0l, aA, 0,0,0);
                aB = MFMA(a2hi[tl][1], s1l, aB, 0,0,0);
                aA = MFMA(a2hi[tl][2], s2h, aA, 0,0,0);
                aB = MFMA(a2hi[tl][3], s3h, aB, 0,0,0);
                aA = MFMA(a2lo[tl][2], s2h, aA, 0,0,0);
                aB = MFMA(a2lo[tl][3], s3h, aB, 0,0,0);
                aA = MFMA(a2hi[tl][2], s2l, aA, 0,0,0);
                aB = MFMA(a2hi[tl][3], s3l, aB, 0,0,0);
                float vi = aA[0]+aB[0], vf = aA[1]+aB[1];
                float vg = aA[2]+aB[2], vo = aA[3]+aB[3];
                c2[tl] = __builtin_fmaf(fsig(vf), c2[tl], fsig(vi)*ftanh(vg));
                float h2n = fsig(vo) * ftanh(c2[tl]);
                if (uvt[tl]) {
                    uint16_t hh = f2bf(h2n);
                    int ad = nn*BST + 64 + ut[tl];
                    Bhi[p0][ad] = hh; Blo[p0][ad] = f2bf(h2n - bf2f(hh));
                }
                part = __builtin_fmaf(wlu[tl], h2n, part);
            }
            // output partials over this wave's units
            part += __shfl_xor(part, 16, 64);
            part += __shfl_xor(part, 32, 64);
            if (quad == 0) wsum[wv*NBB + nn] = part;
        }
        __syncthreads();                                   // bar 2
        xreg = xnext;
    }

    // final output (t = Ttot-1) into obuf, then coalesced dump to global
    if (wv == NW-1) {
        float osum = blv;
#pragma unroll
        for (int w = 0; w < NW; ++w) osum += wsum[w*NBB + nn];
        if (ln < NBB) obuf[(Ttot-1)*NBB + ln] = osum;
    }
    __syncthreads();
    for (int idx = tid; idx < NBB*Ttot; idx += BLK) {
        int b = idx / Ttot, tt = idx - b*Ttot;
        outp[(size_t)(b0 + b)*Ttot + tt] = obuf[tt*NBB + b];
    }
}

extern "C" void kernel_launch(void* const* d_in, const int* in_sizes, int n_in,
                              void* d_out, int out_size, void* d_ws, size_t ws_size,
                              hipStream_t stream) {
    (void)in_sizes; (void)n_in; (void)out_size; (void)d_ws; (void)ws_size;
    lstm_mfma4<<<dim3(Bsz / NBB), dim3(BLK), 0, stream>>>(
        (const float*)d_in[0], (const float*)d_in[1],
        (const float*)d_in[2], (const float*)d_in[3],
        (const float*)d_in[4], (const float*)d_in[5],
        (const float*)d_in[6], (const float*)d_in[7],
        (const float*)d_in[8], (const float*)d_in[9],
        (const float*)d_in[10], (float*)d_out);
}